// Round 3
// baseline (21.229 us; speedup 1.0000x reference)
//
#include <hip/hip_runtime.h>
#include <hip/hip_fp16.h>
#include <math.h>

typedef _Float16 half8 __attribute__((ext_vector_type(8)));
typedef _Float16 half4 __attribute__((ext_vector_type(4)));
typedef float f32x4 __attribute__((ext_vector_type(4)));

#define S_LEN 2048
#define NH 8
#define DH 64
#define HD (NH*DH)
#define BQ 64
#define NT 256
#define CK 64            // keys per LDS chunk (double-buffered)

// Sliding-window attention, f16 MFMA flash kernel, chunked K/V streaming.
// Swapped QK^T: S^T = K*Q^T -> lane (c,g) holds 8 scores for query q0+c.
// PV: O^T = V^T * P^T with K-axis permutation sigma(8g+e)=4g+(e&3)+16*(e>>2)
// so the P fragment is the lane's own 8 probabilities (no repack).
// K/V stream through LDS in 64-key chunks, double-buffered; chunk t+1 global
// loads are issued (into regs) before chunk t's compute so HBM overlaps MFMA.
__global__ __launch_bounds__(NT, 2)
void swa_mfma(const float* __restrict__ qg, const float* __restrict__ kg,
              const float* __restrict__ vg, const int* __restrict__ wptr,
              float* __restrict__ outg)
{
    __shared__ __align__(16) unsigned short Kb[2][CK * DH];  // [key][dim] f16, 16B-chunk swizzle
    __shared__ __align__(16) unsigned short Vb[2][DH * CK];  // [dim][key] f16, 16B-chunk swizzle

    int W = *wptr; if (W > 128) W = 128;
    const int span = BQ + 2 * W;
    const int nch = (span + CK - 1) / CK;

    const int t = threadIdx.x;
    // XCD-aware bijective swizzle (gridDim.x = 512, multiple of 8)
    int bid = blockIdx.x;
    bid = (bid & 7) * (gridDim.x >> 3) + (bid >> 3);
    const int qt = bid & 31, h = (bid >> 5) & 7, b = bid >> 8;
    const int i0 = qt * BQ, s0 = i0 - W;

    const float* kbh = kg + (size_t)b * S_LEN * HD + h * DH;
    const float* vbh = vg + (size_t)b * S_LEN * HD + h * DH;

    // staging geometry: K task (row koff, 8-float col-chunk cr), V task (key-quad, dim-quad)
    const int k_koff = t >> 3, k_cr = t & 7;
    const int v_kq = t >> 4, v_dq = t & 15;

    f32x4 ka[2][2];   // K prefetch regs: 2 rows x 16 floats
    f32x4 va[4];      // V prefetch regs: 4 rows x 4 floats

    auto loadK = [&](int cc) {
        #pragma unroll
        for (int it = 0; it < 2; ++it) {
            const int koff = k_koff + it * 32;
            const int j = s0 + cc * CK + koff;
            f32x4 f0 = {0,0,0,0}, f1 = {0,0,0,0};
            if ((unsigned)j < S_LEN) {
                const float* p = kbh + (size_t)j * HD + k_cr * 8;
                f0 = *(const f32x4*)p; f1 = *(const f32x4*)(p + 4);
            }
            ka[it][0] = f0; ka[it][1] = f1;
        }
    };
    auto writeK = [&](int bufi) {
        #pragma unroll
        for (int it = 0; it < 2; ++it) {
            const int koff = k_koff + it * 32;
            half8 hv;
            #pragma unroll
            for (int e = 0; e < 4; ++e) {
                hv[e]     = (_Float16)ka[it][0][e];
                hv[4 + e] = (_Float16)ka[it][1][e];
            }
            *(half8*)(&Kb[bufi][koff * 64 + ((k_cr ^ (koff & 7)) << 3)]) = hv;
        }
    };
    auto loadV = [&](int cc) {
        #pragma unroll
        for (int jj = 0; jj < 4; ++jj) {
            const int j = s0 + cc * CK + v_kq * 4 + jj;
            f32x4 f = {0,0,0,0};
            if ((unsigned)j < S_LEN) f = *(const f32x4*)(vbh + (size_t)j * HD + v_dq * 4);
            va[jj] = f;
        }
    };
    auto writeV = [&](int bufi) {
        #pragma unroll
        for (int i = 0; i < 4; ++i) {
            const int dim = v_dq * 4 + i;
            half4 w = { (_Float16)va[0][i], (_Float16)va[1][i],
                        (_Float16)va[2][i], (_Float16)va[3][i] };
            const int off = dim * 64 + (((v_kq >> 1) ^ (dim & 7)) << 3) + ((v_kq & 1) << 2);
            *(half4*)(&Vb[bufi][off]) = w;
        }
    };

    // ---- per-lane Q fragments (1/sqrt(D) * log2(e) folded in; exp -> exp2) ----
    const int wid = t >> 6, lane = t & 63, c = lane & 15, g = lane >> 4;
    const int q = i0 + wid * 16 + c;
    const float* qrow = qg + (size_t)b * S_LEN * HD + h * DH + (size_t)q * HD;
    half8 qa0, qa1;
    {
        const float qs = 0.18033688011112042f;  // 0.125 * log2(e)
        f32x4 q0 = *(const f32x4*)(qrow + g * 8);
        f32x4 q1 = *(const f32x4*)(qrow + g * 8 + 4);
        f32x4 q2 = *(const f32x4*)(qrow + 32 + g * 8);
        f32x4 q3 = *(const f32x4*)(qrow + 32 + g * 8 + 4);
        #pragma unroll
        for (int e = 0; e < 4; ++e) {
            qa0[e] = (_Float16)(q0[e] * qs); qa0[4 + e] = (_Float16)(q1[e] * qs);
            qa1[e] = (_Float16)(q2[e] * qs); qa1[4 + e] = (_Float16)(q3[e] * qs);
        }
    }

    const int c7 = c & 7;
    const int ch0 = (g ^ c7) << 3;
    const int ch1 = ((g + 4) ^ c7) << 3;
    int lo = q - W; if (lo < 0) lo = 0;
    int hi = q + W; if (hi > S_LEN - 1) hi = S_LEN - 1;
    const unsigned rng = (unsigned)(hi - lo);

    int ts = wid >> 1;
    const int ts0 = (s0 < 0) ? ((-s0) >> 5) : 0;
    if (ts0 > ts) ts = ts0;
    const int te_w = (16 * wid + 15 + 2 * W) >> 5;
    const int te_s = (S_LEN - 1 - s0) >> 5;
    const int te = te_w < te_s ? te_w : te_s;

    float m = -1e4f, l = 0.f;
    f32x4 o0 = {0,0,0,0}, o1 = {0,0,0,0}, o2 = {0,0,0,0}, o3 = {0,0,0,0};

    // ---- prologue: stage chunk 0 ----
    loadK(0); loadV(0);
    writeK(0); writeV(0);
    __syncthreads();

    for (int cc = 0; cc < nch; ++cc) {
        const int cur = cc & 1;
        const bool pf = (cc + 1 < nch);
        if (pf) { loadK(cc + 1); loadV(cc + 1); }   // global->reg, in flight over compute

        #pragma unroll
        for (int hh = 0; hh < 2; ++hh) {
            const int t32 = 2 * cc + hh;
            if (t32 < ts || t32 > te) continue;

            // ---- QK^T (swapped): S^T = K * Q^T ----
            const unsigned short* krow = &Kb[cur][((hh << 5) + c) * 64];
            half8 k00 = *(const half8*)(krow + ch0);
            half8 k01 = *(const half8*)(krow + ch1);
            half8 k10 = *(const half8*)(krow + 16 * 64 + ch0);
            half8 k11 = *(const half8*)(krow + 16 * 64 + ch1);
            f32x4 st0 = {0,0,0,0}, st1 = {0,0,0,0};
            __builtin_amdgcn_s_setprio(1);
            st0 = __builtin_amdgcn_mfma_f32_16x16x32_f16(k00, qa0, st0, 0, 0, 0);
            st0 = __builtin_amdgcn_mfma_f32_16x16x32_f16(k01, qa1, st0, 0, 0, 0);
            st1 = __builtin_amdgcn_mfma_f32_16x16x32_f16(k10, qa0, st1, 0, 0, 0);
            st1 = __builtin_amdgcn_mfma_f32_16x16x32_f16(k11, qa1, st1, 0, 0, 0);
            __builtin_amdgcn_s_setprio(0);

            // ---- mask + online softmax (exp2 domain, lane-local per query) ----
            const int kb = s0 + t32 * 32 + 4 * g;
            float sv0[4], sv1[4];
            #pragma unroll
            for (int r = 0; r < 4; ++r) {
                sv0[r] = ((unsigned)(kb + r - lo) <= rng)      ? st0[r] : -30000.f;
                sv1[r] = ((unsigned)(kb + 16 + r - lo) <= rng) ? st1[r] : -30000.f;
            }
            float tmax = fmaxf(fmaxf(fmaxf(sv0[0], sv0[1]), fmaxf(sv0[2], sv0[3])),
                               fmaxf(fmaxf(sv1[0], sv1[1]), fmaxf(sv1[2], sv1[3])));
            tmax = fmaxf(tmax, __shfl_xor(tmax, 16));
            tmax = fmaxf(tmax, __shfl_xor(tmax, 32));
            if (__any(tmax > m)) {   // deferred rescale: skip when max didn't grow anywhere
                const float newm = fmaxf(m, tmax);
                const float alpha = exp2f(m - newm);
                m = newm;
                l *= alpha;
                o0 *= alpha; o1 *= alpha; o2 *= alpha; o3 *= alpha;
            }

            float p0[4], p1[4], ls = 0.f;
            #pragma unroll
            for (int r = 0; r < 4; ++r) {
                p0[r] = exp2f(sv0[r] - m);
                p1[r] = exp2f(sv1[r] - m);
                ls += p0[r] + p1[r];
            }
            l += ls;
            half8 pb;
            #pragma unroll
            for (int r = 0; r < 4; ++r) { pb[r] = (_Float16)p0[r]; pb[4 + r] = (_Float16)p1[r]; }

            // ---- PV: O^T += V^T * P^T (same sigma permutation on K-axis) ----
            const int cb = 4 * hh + (g >> 1);
            const int off1 = ((cb ^ c7) << 3) + ((g & 1) << 2);
            const int off2 = (((cb + 2) ^ c7) << 3) + ((g & 1) << 2);
            __builtin_amdgcn_s_setprio(1);
#define PV_STEP(DF, OACC) { \
            const unsigned short* vrow = &Vb[cur][(16 * DF + c) * 64]; \
            half4 vlo = *(const half4*)(vrow + off1); \
            half4 vhi = *(const half4*)(vrow + off2); \
            half8 vf; \
            vf[0]=vlo[0]; vf[1]=vlo[1]; vf[2]=vlo[2]; vf[3]=vlo[3]; \
            vf[4]=vhi[0]; vf[5]=vhi[1]; vf[6]=vhi[2]; vf[7]=vhi[3]; \
            OACC = __builtin_amdgcn_mfma_f32_16x16x32_f16(vf, pb, OACC, 0, 0, 0); }
            PV_STEP(0, o0)
            PV_STEP(1, o1)
            PV_STEP(2, o2)
            PV_STEP(3, o3)
#undef PV_STEP
            __builtin_amdgcn_s_setprio(0);
        }

        if (pf) { writeK(cur ^ 1); writeV(cur ^ 1); }  // vmcnt wait lands here
        __syncthreads();
    }

    // ---- epilogue ----
    l += __shfl_xor(l, 16);
    l += __shfl_xor(l, 32);
    const float inv = 1.0f / l;
    float* orow = outg + (size_t)b * S_LEN * HD + h * DH + (size_t)q * HD + 4 * g;
    { float4 w; w.x=o0[0]*inv; w.y=o0[1]*inv; w.z=o0[2]*inv; w.w=o0[3]*inv; *(float4*)(orow)      = w; }
    { float4 w; w.x=o1[0]*inv; w.y=o1[1]*inv; w.z=o1[2]*inv; w.w=o1[3]*inv; *(float4*)(orow + 16) = w; }
    { float4 w; w.x=o2[0]*inv; w.y=o2[1]*inv; w.z=o2[2]*inv; w.w=o2[3]*inv; *(float4*)(orow + 32) = w; }
    { float4 w; w.x=o3[0]*inv; w.y=o3[1]*inv; w.z=o3[2]*inv; w.w=o3[3]*inv; *(float4*)(orow + 48) = w; }
}

extern "C" void kernel_launch(void* const* d_in, const int* in_sizes, int n_in,
                              void* d_out, int out_size, void* d_ws, size_t ws_size,
                              hipStream_t stream) {
    const float* q = (const float*)d_in[0];
    const float* k = (const float*)d_in[1];
    const float* v = (const float*)d_in[2];
    const int*   w = (const int*)d_in[3];
    float* out = (float*)d_out;

    const int nblocks = 2 * NH * (S_LEN / BQ);   // 512
    swa_mfma<<<dim3(nblocks), dim3(NT), 0, stream>>>(q, k, v, w, out);
}

// Round 4
// 19.590 us; speedup vs baseline: 1.0837x; 1.0837x over previous
//
#include <hip/hip_runtime.h>
#include <hip/hip_fp16.h>
#include <math.h>

typedef _Float16 half8 __attribute__((ext_vector_type(8)));
typedef _Float16 half4 __attribute__((ext_vector_type(4)));
typedef float f32x4 __attribute__((ext_vector_type(4)));

#define S_LEN 2048
#define NH 8
#define DH 64
#define HD (NH*DH)
#define BQ 128
#define SPAN (BQ + 256)      // 384 keys staged per block (W<=128)
#define NT 512               // 8 waves
#define NTILES (SPAN / 32)   // 12
#define SPLIT_T 6            // tiles 0..5 = phase A (keys 0..191), 6..11 = phase B

// Sliding-window attention, f16 MFMA flash kernel.
// Swapped QK^T: S^T = K*Q^T -> lane (c,g) holds 8 scores for query q0+16*wid+c.
// PV: O^T = V^T * P^T with K-axis permutation sigma(8g+e)=4g+(e&3)+16*(e>>2)
// so the P fragment is the lane's own 8 probabilities (no repack).
// Stage-once span=384 (BQ=128 cuts K/V read amplification to 3x), split into
// two 192-key phases: phase-B global loads are issued before phase-A compute
// so HBM latency hides under MFMA+softmax.
__global__ __launch_bounds__(NT, 2)
void swa_mfma(const float* __restrict__ qg, const float* __restrict__ kg,
              const float* __restrict__ vg, const int* __restrict__ wptr,
              float* __restrict__ outg)
{
    __shared__ __align__(16) unsigned short Kl[SPAN * DH];  // [key][dim] f16, 16B-chunk swizzle
    __shared__ __align__(16) unsigned short Vt[DH * SPAN];  // [dim][key] f16, 16B-chunk swizzle

    int W = *wptr; if (W > 128) W = 128;

    const int t = threadIdx.x;
    // XCD-aware bijective swizzle (gridDim.x = 256, multiple of 8):
    // each XCD gets 32 contiguous work-ids = all 16 q-tiles of 2 (b,h) panels.
    int bid = blockIdx.x;
    bid = (bid & 7) * (gridDim.x >> 3) + (bid >> 3);
    const int qt = bid & 15, h = (bid >> 4) & 7, b = bid >> 7;
    const int i0 = qt * BQ, s0 = i0 - W;

    const float* kbh = kg + (size_t)b * S_LEN * HD + h * DH;
    const float* vbh = vg + (size_t)b * S_LEN * HD + h * DH;

    const int wid = t >> 6, lane = t & 63, c = lane & 15, g = lane >> 4;
    const int q = i0 + wid * 16 + c;

    // ---- Q loads issued first (overlap with staging) ----
    const float* qrow = qg + (size_t)b * S_LEN * HD + h * DH + (size_t)q * HD;
    const f32x4 qf0 = *(const f32x4*)(qrow + g * 8);
    const f32x4 qf1 = *(const f32x4*)(qrow + g * 8 + 4);
    const f32x4 qf2 = *(const f32x4*)(qrow + 32 + g * 8);
    const f32x4 qf3 = *(const f32x4*)(qrow + 32 + g * 8 + 4);

    // ---- stage phase A: keys [0, 192) ----
    #pragma unroll
    for (int it = 0; it < 3; ++it) {                 // K: 1536 tasks / 512 thr = 3
        const int task = t + it * NT;
        const int koff = task >> 3, cr = task & 7;
        const int j = s0 + koff;
        f32x4 f0 = {0,0,0,0}, f1 = {0,0,0,0};
        if ((unsigned)j < S_LEN) {
            const float* p = kbh + (size_t)j * HD + cr * 8;
            f0 = *(const f32x4*)p; f1 = *(const f32x4*)(p + 4);
        }
        half8 hv;
        #pragma unroll
        for (int e = 0; e < 4; ++e) { hv[e] = (_Float16)f0[e]; hv[4+e] = (_Float16)f1[e]; }
        *(half8*)(&Kl[koff * 64 + ((cr ^ (koff & 7)) << 3)]) = hv;
    }
    for (int task = t; task < 768; task += NT) {     // V: 768 key-quad tasks
        const int kq = task >> 4, dq = task & 15;
        f32x4 r[4];
        #pragma unroll
        for (int jj = 0; jj < 4; ++jj) {
            const int j = s0 + kq * 4 + jj;
            f32x4 f = {0,0,0,0};
            if ((unsigned)j < S_LEN) f = *(const f32x4*)(vbh + (size_t)j * HD + dq * 4);
            r[jj] = f;
        }
        #pragma unroll
        for (int i = 0; i < 4; ++i) {
            const int dim = dq * 4 + i;
            half4 w = { (_Float16)r[0][i], (_Float16)r[1][i],
                        (_Float16)r[2][i], (_Float16)r[3][i] };
            *(half4*)(&Vt[dim * SPAN + (((kq >> 1) ^ (dim & 7)) << 3) + ((kq & 1) << 2)]) = w;
        }
    }

    // ---- Q fragments (1/sqrt(D)*log2(e) folded; exp -> exp2 domain) ----
    half8 qa0, qa1;
    {
        const float qs = 0.18033688011112042f;  // 0.125 * log2(e)
        #pragma unroll
        for (int e = 0; e < 4; ++e) {
            qa0[e] = (_Float16)(qf0[e] * qs); qa0[4+e] = (_Float16)(qf1[e] * qs);
            qa1[e] = (_Float16)(qf2[e] * qs); qa1[4+e] = (_Float16)(qf3[e] * qs);
        }
    }

    const int c7 = c & 7;
    const int ch0 = (g ^ c7) << 3;
    const int ch1 = ((g + 4) ^ c7) << 3;
    int lo = q - W; if (lo < 0) lo = 0;
    int hi = q + W; if (hi > S_LEN - 1) hi = S_LEN - 1;
    const unsigned rng = (unsigned)(hi - lo);

    int ts = wid >> 1;
    const int ts0 = (s0 < 0) ? ((-s0) >> 5) : 0;
    if (ts0 > ts) ts = ts0;
    const int te_w = (16 * wid + 15 + 2 * W) >> 5;
    const int te_s = (S_LEN - 1 - s0) >> 5;
    const int te = te_w < te_s ? te_w : te_s;

    float m = -1e4f, l = 0.f;
    f32x4 o0 = {0,0,0,0}, o1 = {0,0,0,0}, o2 = {0,0,0,0}, o3 = {0,0,0,0};

    __syncthreads();   // phase-A tile ready

    // ---- issue phase-B global loads (keys [192,384)) into registers ----
    f32x4 kpf[3][2];
    #pragma unroll
    for (int it = 0; it < 3; ++it) {
        const int task = 1536 + t + it * NT;
        const int koff = task >> 3, cr = task & 7;
        const int j = s0 + koff;
        f32x4 f0 = {0,0,0,0}, f1 = {0,0,0,0};
        if ((unsigned)j < S_LEN) {
            const float* p = kbh + (size_t)j * HD + cr * 8;
            f0 = *(const f32x4*)p; f1 = *(const f32x4*)(p + 4);
        }
        kpf[it][0] = f0; kpf[it][1] = f1;
    }
    f32x4 vpf[2][4];
    #pragma unroll
    for (int it = 0; it < 2; ++it) {
        const int task = 768 + t + it * NT;
        #pragma unroll
        for (int jj = 0; jj < 4; ++jj) {
            f32x4 f = {0,0,0,0};
            if (task < 1536) {
                const int kq = task >> 4, dq = task & 15;
                const int j = s0 + kq * 4 + jj;
                if ((unsigned)j < S_LEN) f = *(const f32x4*)(vbh + (size_t)j * HD + dq * 4);
            }
            vpf[it][jj] = f;
        }
    }

    auto computeTile = [&](int t32) {
        // ---- QK^T (swapped): S^T = K * Q^T ----
        const unsigned short* krow = &Kl[(t32 * 32 + c) * 64];
        half8 k00 = *(const half8*)(krow + ch0);
        half8 k01 = *(const half8*)(krow + ch1);
        half8 k10 = *(const half8*)(krow + 16 * 64 + ch0);
        half8 k11 = *(const half8*)(krow + 16 * 64 + ch1);
        f32x4 st0 = {0,0,0,0}, st1 = {0,0,0,0};
        __builtin_amdgcn_s_setprio(1);
        st0 = __builtin_amdgcn_mfma_f32_16x16x32_f16(k00, qa0, st0, 0, 0, 0);
        st0 = __builtin_amdgcn_mfma_f32_16x16x32_f16(k01, qa1, st0, 0, 0, 0);
        st1 = __builtin_amdgcn_mfma_f32_16x16x32_f16(k10, qa0, st1, 0, 0, 0);
        st1 = __builtin_amdgcn_mfma_f32_16x16x32_f16(k11, qa1, st1, 0, 0, 0);
        __builtin_amdgcn_s_setprio(0);

        // ---- mask + online softmax (lane-local per query) ----
        const int kb = s0 + t32 * 32 + 4 * g;
        float sv0[4], sv1[4];
        #pragma unroll
        for (int r = 0; r < 4; ++r) {
            sv0[r] = ((unsigned)(kb + r - lo) <= rng)      ? st0[r] : -30000.f;
            sv1[r] = ((unsigned)(kb + 16 + r - lo) <= rng) ? st1[r] : -30000.f;
        }
        float tmax = fmaxf(fmaxf(fmaxf(sv0[0], sv0[1]), fmaxf(sv0[2], sv0[3])),
                           fmaxf(fmaxf(sv1[0], sv1[1]), fmaxf(sv1[2], sv1[3])));
        tmax = fmaxf(tmax, __shfl_xor(tmax, 16));
        tmax = fmaxf(tmax, __shfl_xor(tmax, 32));
        if (__any(tmax > m)) {   // deferred rescale
            const float newm = fmaxf(m, tmax);
            const float alpha = exp2f(m - newm);
            m = newm;
            l *= alpha;
            o0 *= alpha; o1 *= alpha; o2 *= alpha; o3 *= alpha;
        }
        float p0[4], p1[4], ls = 0.f;
        #pragma unroll
        for (int r = 0; r < 4; ++r) {
            p0[r] = exp2f(sv0[r] - m);
            p1[r] = exp2f(sv1[r] - m);
            ls += p0[r] + p1[r];
        }
        l += ls;
        half8 pb;
        #pragma unroll
        for (int r = 0; r < 4; ++r) { pb[r] = (_Float16)p0[r]; pb[4+r] = (_Float16)p1[r]; }

        // ---- PV: O^T += V^T * P^T ----
        const int cb = 4 * t32 + (g >> 1);
        const int off1 = ((cb ^ c7) << 3) + ((g & 1) << 2);
        const int off2 = (((cb + 2) ^ c7) << 3) + ((g & 1) << 2);
        __builtin_amdgcn_s_setprio(1);
#define PV_STEP(DF, OACC) { \
        const unsigned short* vrow = &Vt[(16 * DF + c) * SPAN]; \
        half4 vlo = *(const half4*)(vrow + off1); \
        half4 vhi = *(const half4*)(vrow + off2); \
        half8 vf; \
        vf[0]=vlo[0]; vf[1]=vlo[1]; vf[2]=vlo[2]; vf[3]=vlo[3]; \
        vf[4]=vhi[0]; vf[5]=vhi[1]; vf[6]=vhi[2]; vf[7]=vhi[3]; \
        OACC = __builtin_amdgcn_mfma_f32_16x16x32_f16(vf, pb, OACC, 0, 0, 0); }
        PV_STEP(0, o0)
        PV_STEP(1, o1)
        PV_STEP(2, o2)
        PV_STEP(3, o3)
#undef PV_STEP
        __builtin_amdgcn_s_setprio(0);
    };

    // ---- compute phase A (tiles ts..min(te,5)) ----
    for (int t32 = ts; t32 <= te && t32 < SPLIT_T; ++t32) computeTile(t32);

    // ---- write phase-B tile to LDS (vmcnt waits land here) ----
    #pragma unroll
    for (int it = 0; it < 3; ++it) {
        const int task = 1536 + t + it * NT;
        const int koff = task >> 3, cr = task & 7;
        half8 hv;
        #pragma unroll
        for (int e = 0; e < 4; ++e) { hv[e] = (_Float16)kpf[it][0][e]; hv[4+e] = (_Float16)kpf[it][1][e]; }
        *(half8*)(&Kl[koff * 64 + ((cr ^ (koff & 7)) << 3)]) = hv;
    }
    #pragma unroll
    for (int it = 0; it < 2; ++it) {
        const int task = 768 + t + it * NT;
        if (task < 1536) {
            const int kq = task >> 4, dq = task & 15;
            #pragma unroll
            for (int i = 0; i < 4; ++i) {
                const int dim = dq * 4 + i;
                half4 w = { (_Float16)vpf[it][0][i], (_Float16)vpf[it][1][i],
                            (_Float16)vpf[it][2][i], (_Float16)vpf[it][3][i] };
                *(half4*)(&Vt[dim * SPAN + (((kq >> 1) ^ (dim & 7)) << 3) + ((kq & 1) << 2)]) = w;
            }
        }
    }
    __syncthreads();

    // ---- compute phase B (tiles max(ts,6)..te) ----
    for (int t32 = (ts > SPLIT_T ? ts : SPLIT_T); t32 <= te; ++t32) computeTile(t32);

    // ---- epilogue ----
    l += __shfl_xor(l, 16);
    l += __shfl_xor(l, 32);
    const float inv = 1.0f / l;
    float* orow = outg + (size_t)b * S_LEN * HD + h * DH + (size_t)q * HD + 4 * g;
    { float4 w; w.x=o0[0]*inv; w.y=o0[1]*inv; w.z=o0[2]*inv; w.w=o0[3]*inv; *(float4*)(orow)      = w; }
    { float4 w; w.x=o1[0]*inv; w.y=o1[1]*inv; w.z=o1[2]*inv; w.w=o1[3]*inv; *(float4*)(orow + 16) = w; }
    { float4 w; w.x=o2[0]*inv; w.y=o2[1]*inv; w.z=o2[2]*inv; w.w=o2[3]*inv; *(float4*)(orow + 32) = w; }
    { float4 w; w.x=o3[0]*inv; w.y=o3[1]*inv; w.z=o3[2]*inv; w.w=o3[3]*inv; *(float4*)(orow + 48) = w; }
}

extern "C" void kernel_launch(void* const* d_in, const int* in_sizes, int n_in,
                              void* d_out, int out_size, void* d_ws, size_t ws_size,
                              hipStream_t stream) {
    const float* q = (const float*)d_in[0];
    const float* k = (const float*)d_in[1];
    const float* v = (const float*)d_in[2];
    const int*   w = (const int*)d_in[3];
    float* out = (float*)d_out;

    const int nblocks = 2 * NH * (S_LEN / BQ);   // 256
    swa_mfma<<<dim3(nblocks), dim3(NT), 0, stream>>>(q, k, v, w, out);
}